// Round 4
// baseline (401.307 us; speedup 1.0000x reference)
//
#include <hip/hip_runtime.h>

#define NSEQ 2048
#define DMODEL 1024
#define NHEAD 16
#define HDIM 64
#define NBATCH 4
#define MTOT 8192
#define ATT_SCALE 0.125f
#define LOG2E 1.4426950408889634f

typedef __bf16 bf16x8 __attribute__((ext_vector_type(8)));
typedef float f32x4 __attribute__((ext_vector_type(4)));
typedef unsigned int u32x4 __attribute__((ext_vector_type(4)));
typedef unsigned short u16;
typedef unsigned int u32;
typedef unsigned long long u64;

__device__ __forceinline__ u16 f2bf(float f) {
  u32 u = __builtin_bit_cast(u32, f);
  return (u16)((u + 0x7fffu + ((u >> 16) & 1u)) >> 16);
}

__device__ __forceinline__ void gload_lds16(const void* g, void* l) {
  __builtin_amdgcn_global_load_lds(
      (__attribute__((address_space(1))) const u32*)g,
      (__attribute__((address_space(3))) u32*)l, 16, 0, 0);
}

// ---------------- cast fp32 -> bf16 (x) ----------------
__global__ __launch_bounds__(256) void cast_f32_bf16(const float* __restrict__ in,
                                                     u16* __restrict__ out, int n) {
  int i = (blockIdx.x * 256 + threadIdx.x) * 4;
  if (i >= n) return;
  float4 v = *(const float4*)(in + i);
  ushort4 o;
  o.x = f2bf(v.x); o.y = f2bf(v.y); o.z = f2bf(v.z); o.w = f2bf(v.w);
  *(ushort4*)(out + i) = o;
}

// ---------------- cast 4 weights -> contiguous bf16 block ----------------
__global__ __launch_bounds__(256) void cast_w4(const float* __restrict__ a,
                                               const float* __restrict__ b,
                                               const float* __restrict__ c,
                                               const float* __restrict__ d,
                                               u16* __restrict__ out) {
  int bid = blockIdx.x;
  int which = bid >> 10, lb = bid & 1023;
  const float* src = (which == 0) ? a : (which == 1) ? b : (which == 2) ? c : d;
  int i = (lb * 256 + threadIdx.x) * 4;
  float4 v = *(const float4*)(src + i);
  ushort4 o;
  o.x = f2bf(v.x); o.y = f2bf(v.y); o.z = f2bf(v.z); o.w = f2bf(v.w);
  *(ushort4*)(out + (size_t)which * 1048576 + i) = o;
}

// ---------------- pack mask int32 -> bit per element ----------------
__global__ __launch_bounds__(256) void pack_mask(const int* __restrict__ mask,
                                                 u64* __restrict__ bits) {
  int wave = (blockIdx.x * 256 + threadIdx.x) >> 6;
  int lane = threadIdx.x & 63;
  const int* row = mask + (size_t)wave * NSEQ;
  u64* out = bits + (size_t)wave * 32;
  for (int c = 0; c < 32; ++c) {
    int v = row[c * 64 + lane];
    u64 bl = __ballot(v != 0);
    if (lane == 0) out[c] = bl;
  }
}

// ---------------- fused QKV GEMM: C[m,n] = sum_k A[m,k]*Wc[n,k], N=3072 ----------------
// bn 0..7 -> Q [B,H,N,64]; 8..15 -> K [B,H,N,64]; 16..23 -> V^T [B,H,64,NSEQ]
__global__ __launch_bounds__(256) void gemm_qkv(const u16* __restrict__ A,
                                                const u16* __restrict__ Wc,
                                                u16* __restrict__ qo,
                                                u16* __restrict__ ko,
                                                u16* __restrict__ vo) {
  __shared__ __align__(16) u16 Al[128 * 64];
  __shared__ __align__(16) u16 Bl[128 * 64];
  const int tid = threadIdx.x;
  const int w = tid >> 6, l = tid & 63;
  const int l15 = l & 15, l4 = l >> 4;
  const int bm = blockIdx.x, bn = blockIdx.y;
  const int wm = w >> 1, wn = w & 1;

  f32x4 acc[4][4] = {};

  for (int ks = 0; ks < 1024; ks += 64) {
    __syncthreads();
#pragma unroll
    for (int c = 0; c < 4; ++c) {
      int g = w * 256 + c * 64 + l;
      int row = g >> 3, gc = g & 7;
      int sgc = gc ^ (row & 7);
      gload_lds16(A + (size_t)(bm * 128 + row) * 1024 + ks + sgc * 8, &Al[g * 8]);
      gload_lds16(Wc + (size_t)(bn * 128 + row) * 1024 + ks + sgc * 8, &Bl[g * 8]);
    }
    __syncthreads();
#pragma unroll
    for (int kc = 0; kc < 2; ++kc) {
      bf16x8 af[4], bfr[4];
#pragma unroll
      for (int mi = 0; mi < 4; ++mi) {
        int row = wm * 64 + mi * 16 + l15;
        int gc2 = (kc * 4 + l4) ^ (row & 7);
        af[mi] = *(const bf16x8*)&Al[row * 64 + gc2 * 8];
      }
#pragma unroll
      for (int ni = 0; ni < 4; ++ni) {
        int row = wn * 64 + ni * 16 + l15;
        int gc2 = (kc * 4 + l4) ^ (row & 7);
        bfr[ni] = *(const bf16x8*)&Bl[row * 64 + gc2 * 8];
      }
#pragma unroll
      for (int mi = 0; mi < 4; ++mi)
#pragma unroll
        for (int ni = 0; ni < 4; ++ni)
          acc[mi][ni] = __builtin_amdgcn_mfma_f32_16x16x32_bf16(af[mi], bfr[ni],
                                                                acc[mi][ni], 0, 0, 0);
    }
  }

  const int which = bn >> 3;
#pragma unroll
  for (int mi = 0; mi < 4; ++mi)
#pragma unroll
    for (int ni = 0; ni < 4; ++ni)
#pragma unroll
      for (int r = 0; r < 4; ++r) {
        int m = bm * 128 + wm * 64 + mi * 16 + l4 * 4 + r;
        int n = (bn & 7) * 128 + wn * 64 + ni * 16 + l15;
        int b = m >> 11, row = m & 2047, h = n >> 6, d = n & 63;
        u16 val = f2bf(acc[mi][ni][r]);
        size_t bh = (size_t)(b * 16 + h);
        if (which == 0)      qo[(bh * NSEQ + row) * 64 + d] = val;
        else if (which == 1) ko[(bh * NSEQ + row) * 64 + d] = val;
        else                 vo[(bh * 64 + d) * NSEQ + row] = val;
      }
}

// ---------------- final GEMM: out[m,n] = sum_k A[m,k]*W[n,k], fp32 out ----------------
__global__ __launch_bounds__(256) void gemm_out(const u16* __restrict__ A,
                                                const u16* __restrict__ W,
                                                float* __restrict__ C) {
  __shared__ __align__(16) u16 Al[128 * 64];
  __shared__ __align__(16) u16 Bl[128 * 64];
  const int tid = threadIdx.x;
  const int w = tid >> 6, l = tid & 63;
  const int l15 = l & 15, l4 = l >> 4;
  const int bm = blockIdx.x, bn = blockIdx.y;
  const int wm = w >> 1, wn = w & 1;

  f32x4 acc[4][4] = {};

  for (int ks = 0; ks < 1024; ks += 64) {
    __syncthreads();
#pragma unroll
    for (int c = 0; c < 4; ++c) {
      int g = w * 256 + c * 64 + l;
      int row = g >> 3, gc = g & 7;
      int sgc = gc ^ (row & 7);
      gload_lds16(A + (size_t)(bm * 128 + row) * 1024 + ks + sgc * 8, &Al[g * 8]);
      gload_lds16(W + (size_t)(bn * 128 + row) * 1024 + ks + sgc * 8, &Bl[g * 8]);
    }
    __syncthreads();
#pragma unroll
    for (int kc = 0; kc < 2; ++kc) {
      bf16x8 af[4], bfr[4];
#pragma unroll
      for (int mi = 0; mi < 4; ++mi) {
        int row = wm * 64 + mi * 16 + l15;
        int gc2 = (kc * 4 + l4) ^ (row & 7);
        af[mi] = *(const bf16x8*)&Al[row * 64 + gc2 * 8];
      }
#pragma unroll
      for (int ni = 0; ni < 4; ++ni) {
        int row = wn * 64 + ni * 16 + l15;
        int gc2 = (kc * 4 + l4) ^ (row & 7);
        bfr[ni] = *(const bf16x8*)&Bl[row * 64 + gc2 * 8];
      }
#pragma unroll
      for (int mi = 0; mi < 4; ++mi)
#pragma unroll
        for (int ni = 0; ni < 4; ++ni)
          acc[mi][ni] = __builtin_amdgcn_mfma_f32_16x16x32_bf16(af[mi], bfr[ni],
                                                                acc[mi][ni], 0, 0, 0);
    }
  }

#pragma unroll
  for (int mi = 0; mi < 4; ++mi)
#pragma unroll
    for (int ni = 0; ni < 4; ++ni)
#pragma unroll
      for (int r = 0; r < 4; ++r) {
        int m = bm * 128 + wm * 64 + mi * 16 + l4 * 4 + r;
        int n = bn * 128 + wn * 64 + ni * 16 + l15;
        C[(size_t)m * 1024 + n] = acc[mi][ni][r];
      }
}

// ---------------- flash attention ----------------
// Swapped QK^T + register softmax + K-row permutation so PV A-slots are standard
// (P direct from cvt_pk regs, V as b128 reads). alibi/mask prefetched (t+1) into
// registers; counted-vmcnt raw barrier (never drains in loop). KT=64, dbuf.
__global__ __launch_bounds__(256, 4) void attn_kernel(
    const u16* __restrict__ q, const u16* __restrict__ k, const u16* __restrict__ vT,
    const float* __restrict__ alibi, const u64* __restrict__ mbits,
    u16* __restrict__ o) {
  __shared__ __align__(16) u16 Kl[2][64 * 64];
  __shared__ __align__(16) u16 Vl[2][64 * 64];

  const int tid = threadIdx.x, w = tid >> 6, l = tid & 63;
  const int l15 = l & 15, l4 = l >> 4;
  const int W = blockIdx.x;
  const int W2 = (W & 7) * 256 + (W >> 3);
  const int qb = W2 & 31, Y = W2 >> 5;
  const int h = Y >> 2, b = Y & 3, bh = b * 16 + h;
  const int wq0 = qb * 64 + w * 16;
  const int myq = wq0 + l15;

  // Q fragment (rows = l15)
  bf16x8 aq[2];
  {
    const u16* qrow = q + ((size_t)bh * NSEQ + myq) * 64;
    aq[0] = *(const bf16x8*)(qrow + l4 * 8);
    aq[1] = *(const bf16x8*)(qrow + 32 + l4 * 8);
  }

  // staging pointers. K rows permuted: LDS row p holds global row
  // 32*(p>>5) + 8*((p>>2)&3) + 4*((p>>4)&1) + (p&3)  -> S^T k-distribution
  // matches the standard PV A-slot order.
  const u16* kg[2]; const u16* vg[2];
#pragma unroll
  for (int c = 0; c < 2; ++c) {
    int g = w * 128 + c * 64 + l;
    int row = g >> 3, gc = g & 7, sgc = gc ^ (row & 7);
    int srow = (row & 0x23) | (((row >> 2) & 3) << 3) | (((row >> 4) & 1) << 2);
    kg[c] = k + ((size_t)bh * NSEQ + srow) * 64 + sgc * 8;
    vg[c] = vT + ((size_t)bh * 64 + row) * NSEQ + sgc * 8;
  }

  // per-lane alibi / mask pointers (permuted k: lane covers k = 8*l4 + {0..3,4..7} +32c)
  const float* alp = alibi + (size_t)h * NSEQ * NSEQ + (size_t)myq * NSEQ + 8 * l4;
  const u64* mrp = mbits + ((size_t)b * NSEQ + myq) * 32;

  // LDS read offsets (K and V identical pattern)
  const int kfr[2] = { l15 * 128 + (((0 + l4) ^ (l15 & 7)) << 4),
                       l15 * 128 + (((4 + l4) ^ (l15 & 7)) << 4) };

  f32x4 oacc[4] = {};          // q = wq0 + l4*4 + r, d = db*16 + l15
  float m_run = -3.0e38f, l_run = 0.f;

  auto stage = [&](u16* KB, u16* VB) {
#pragma unroll
    for (int c = 0; c < 2; ++c) {
      gload_lds16(kg[c], (char*)KB + (w * 128 + c * 64 + l) * 16);
      kg[c] += 4096;
      gload_lds16(vg[c], (char*)VB + (w * 128 + c * 64 + l) * 16);
      vg[c] += 64;
    }
  };

  auto loadal = [&](float4* a, u64& m, int t) {
    a[0] = *(const float4*)(alp + t * 64);
    a[1] = *(const float4*)(alp + t * 64 + 4);
    a[2] = *(const float4*)(alp + t * 64 + 32);
    a[3] = *(const float4*)(alp + t * 64 + 36);
    m = mrp[t];
  };

  float4 alA[4], alB[4];
  u64 mbA, mbB;

  // prologue: stage tile0 (4 vmem) + alibi/mask t0 (5 vmem). No sync needed;
  // body0's vmcnt(5) drains them.
  stage(Kl[0], Vl[0]);
  loadal(alA, mbA, 0);

  auto body = [&](const u16* KB, const u16* VB, u16* KN, u16* VN,
                  const float4* alc, u64 mbc, float4* aln, u64& mbn,
                  int t, bool dost) {
    if (dost) {
      loadal(aln, mbn, t + 1);                       // 5 vmem for t+1
      asm volatile("s_waitcnt vmcnt(5)" ::: "memory");  // prev stage done; new 5 in flight
    } else {
      asm volatile("s_waitcnt vmcnt(0)" ::: "memory");
    }
    __builtin_amdgcn_s_barrier();
    if (dost) stage(KN, VN);                          // safe: all waves passed barrier

    // S^T = K Q^T : lane q=l15; k rows permuted by staging
    __builtin_amdgcn_s_setprio(1);
    f32x4 st[4];
#pragma unroll
    for (int kb = 0; kb < 4; ++kb) {
      f32x4 z = {0.f, 0.f, 0.f, 0.f};
      st[kb] = z;
#pragma unroll
      for (int kc = 0; kc < 2; ++kc) {
        bf16x8 bk = *(const bf16x8*)((const char*)KB + kfr[kc] + kb * 2048);
        st[kb] = __builtin_amdgcn_mfma_f32_16x16x32_bf16(bk, aq[kc], st[kb], 0, 0, 0);
      }
    }
    __builtin_amdgcn_s_setprio(0);

    // scale + alibi (permuted layout: (kb,r) -> global k = 32*(kb>>1)+8*l4+4*(kb&1)+r)
#pragma unroll
    for (int kb = 0; kb < 4; ++kb)
#pragma unroll
      for (int r = 0; r < 4; ++r)
        st[kb][r] = fmaf(st[kb][r], ATT_SCALE, alc[kb][r]);
    if (!__all(mbc == ~0ull)) {
#pragma unroll
      for (int kb = 0; kb < 4; ++kb)
#pragma unroll
        for (int r = 0; r < 4; ++r) {
          int bit = 32 * (kb >> 1) + 8 * l4 + 4 * (kb & 1) + r;
          if (!((mbc >> bit) & 1)) st[kb][r] = -3.0e38f;
        }
    }

    // row max: in-lane tree + xor16 + xor32
    float m0 = fmaxf(fmaxf(st[0][0], st[0][1]), fmaxf(st[0][2], st[0][3]));
    float m1 = fmaxf(fmaxf(st[1][0], st[1][1]), fmaxf(st[1][2], st[1][3]));
    float m2 = fmaxf(fmaxf(st[2][0], st[2][1]), fmaxf(st[2][2], st[2][3]));
    float m3 = fmaxf(fmaxf(st[3][0], st[3][1]), fmaxf(st[3][2], st[3][3]));
    float tm = fmaxf(fmaxf(m0, m1), fmaxf(m2, m3));
    tm = fmaxf(tm, __shfl_xor(tm, 16));
    tm = fmaxf(tm, __shfl_xor(tm, 32));

    // defer-max rescale
    if (__any(tm > m_run + 4.0f)) {
      float mn = fmaxf(m_run, tm);
      float fac = exp2f((m_run - mn) * LOG2E);
      l_run *= fac;
      m_run = mn;
#pragma unroll
      for (int r = 0; r < 4; ++r) {
        float fr = __shfl(fac, l4 * 4 + r);
#pragma unroll
        for (int db = 0; db < 4; ++db) oacc[db][r] *= fr;
      }
    }

    // exp + sum
    float negm = -m_run * LOG2E;
    float p[16];
#pragma unroll
    for (int kb = 0; kb < 4; ++kb)
#pragma unroll
      for (int r = 0; r < 4; ++r)
        p[kb * 4 + r] = exp2f(fmaf(st[kb][r], LOG2E, negm));
    float s0 = (p[0] + p[1]) + (p[2] + p[3]);
    float s1 = (p[4] + p[5]) + (p[6] + p[7]);
    float s2 = (p[8] + p[9]) + (p[10] + p[11]);
    float s3 = (p[12] + p[13]) + (p[14] + p[15]);
    float ts = (s0 + s1) + (s2 + s3);
    ts += __shfl_xor(ts, 16);
    ts += __shfl_xor(ts, 32);
    l_run += ts;

    // pack P -> bf16 pairs; with the K-row permutation these are directly the
    // standard A-slots: pa[c] slot j  <->  global k = 32c + 8*l4 + j
    u32 Wp[8];
#pragma unroll
    for (int i = 0; i < 8; ++i)
      asm("v_cvt_pk_bf16_f32 %0, %1, %2" : "=v"(Wp[i]) : "v"(p[2 * i]), "v"(p[2 * i + 1]));

    // O += P V  (V as contiguous b128, same swizzle pattern as K)
    __builtin_amdgcn_s_setprio(1);
#pragma unroll
    for (int c = 0; c < 2; ++c) {
      u32x4 wv = {Wp[4 * c], Wp[4 * c + 1], Wp[4 * c + 2], Wp[4 * c + 3]};
      bf16x8 pa = __builtin_bit_cast(bf16x8, wv);
#pragma unroll
      for (int db = 0; db < 4; ++db) {
        bf16x8 bv = *(const bf16x8*)((const char*)VB + kfr[c] + db * 2048);
        oacc[db] = __builtin_amdgcn_mfma_f32_16x16x32_bf16(pa, bv, oacc[db], 0, 0, 0);
      }
    }
    __builtin_amdgcn_s_setprio(0);
  };

  for (int t2 = 0; t2 < 16; ++t2) {
    body(Kl[0], Vl[0], Kl[1], Vl[1], alA, mbA, alB, mbB, t2 * 2, true);
    body(Kl[1], Vl[1], Kl[0], Vl[0], alB, mbB, alA, mbA, t2 * 2 + 1, t2 < 15);
  }

  // normalize + write O (q = wq0 + l4*4 + r, d = db*16 + l15)
#pragma unroll
  for (int r = 0; r < 4; ++r) {
    float lr = __shfl(l_run, l4 * 4 + r);
    float inv = __builtin_amdgcn_rcpf(lr);
    int qq = wq0 + l4 * 4 + r;
#pragma unroll
    for (int db = 0; db < 4; ++db) {
      int d = db * 16 + l15;
      o[((size_t)b * NSEQ + qq) * DMODEL + h * 64 + d] = f2bf(oacc[db][r] * inv);
    }
  }
}

extern "C" void kernel_launch(void* const* d_in, const int* in_sizes, int n_in,
                              void* d_out, int out_size, void* d_ws, size_t ws_size,
                              hipStream_t stream) {
  (void)in_sizes; (void)n_in; (void)out_size; (void)ws_size;
  const float* x = (const float*)d_in[0];
  const int* mask = (const int*)d_in[1];
  const float* alibi = (const float*)d_in[2];
  const float* Wq = (const float*)d_in[3];
  const float* Wk = (const float*)d_in[4];
  const float* Wv = (const float*)d_in[5];
  const float* Wo = (const float*)d_in[6];
  float* out = (float*)d_out;

  char* ws = (char*)d_ws;
  const size_t MB = 1u << 20;
  u16* xb  = (u16*)(ws + 0 * MB);    // 16 MB
  u16* wqb = (u16*)(ws + 16 * MB);   // 2 MB (wq,wk,wv,wo contiguous 8 MB)
  u16* wob = (u16*)(ws + 22 * MB);
  u16* qb  = (u16*)(ws + 24 * MB);   // 16 MB  [B,H,N,64]
  u16* kb  = (u16*)(ws + 40 * MB);   // 16 MB  [B,H,N,64]
  u16* vT  = (u16*)(ws + 56 * MB);   // 16 MB  [B,H,64,N]
  u16* ob  = (u16*)(ws + 72 * MB);   // 16 MB  [B,N,1024]
  u64* mbits = (u64*)(ws + 88 * MB); // 2 MB   [B*N][32]

  cast_f32_bf16<<<8192, 256, 0, stream>>>(x, xb, MTOT * DMODEL);
  cast_w4<<<4096, 256, 0, stream>>>(Wq, Wk, Wv, Wo, wqb);
  pack_mask<<<2048, 256, 0, stream>>>(mask, mbits);

  gemm_qkv<<<dim3(64, 24), 256, 0, stream>>>(xb, wqb, qb, kb, vT);

  attn_kernel<<<2048, 256, 0, stream>>>(qb, kb, vT, alibi, mbits, ob);

  gemm_out<<<dim3(64, 8), 256, 0, stream>>>(ob, wob, out);
}

// Round 5
// 397.862 us; speedup vs baseline: 1.0087x; 1.0087x over previous
//
#include <hip/hip_runtime.h>

#define NSEQ 2048
#define DMODEL 1024
#define NHEAD 16
#define HDIM 64
#define NBATCH 4
#define MTOT 8192
#define ATT_SCALE 0.125f
#define LOG2E 1.4426950408889634f

typedef __bf16 bf16x8 __attribute__((ext_vector_type(8)));
typedef float f32x4 __attribute__((ext_vector_type(4)));
typedef unsigned int u32x4 __attribute__((ext_vector_type(4)));
typedef unsigned short u16;
typedef unsigned int u32;
typedef unsigned long long u64;

__device__ __forceinline__ u16 f2bf(float f) {
  u32 u = __builtin_bit_cast(u32, f);
  return (u16)((u + 0x7fffu + ((u >> 16) & 1u)) >> 16);
}

__device__ __forceinline__ void gload_lds16(const void* g, void* l) {
  __builtin_amdgcn_global_load_lds(
      (__attribute__((address_space(1))) const u32*)g,
      (__attribute__((address_space(3))) u32*)l, 16, 0, 0);
}

// ---------------- cast fp32 -> bf16 (x) ----------------
__global__ __launch_bounds__(256) void cast_f32_bf16(const float* __restrict__ in,
                                                     u16* __restrict__ out, int n) {
  int i = (blockIdx.x * 256 + threadIdx.x) * 4;
  if (i >= n) return;
  float4 v = *(const float4*)(in + i);
  ushort4 o;
  o.x = f2bf(v.x); o.y = f2bf(v.y); o.z = f2bf(v.z); o.w = f2bf(v.w);
  *(ushort4*)(out + i) = o;
}

// ---------------- cast 4 weights -> contiguous bf16 block ----------------
__global__ __launch_bounds__(256) void cast_w4(const float* __restrict__ a,
                                               const float* __restrict__ b,
                                               const float* __restrict__ c,
                                               const float* __restrict__ d,
                                               u16* __restrict__ out) {
  int bid = blockIdx.x;
  int which = bid >> 10, lb = bid & 1023;
  const float* src = (which == 0) ? a : (which == 1) ? b : (which == 2) ? c : d;
  int i = (lb * 256 + threadIdx.x) * 4;
  float4 v = *(const float4*)(src + i);
  ushort4 o;
  o.x = f2bf(v.x); o.y = f2bf(v.y); o.z = f2bf(v.z); o.w = f2bf(v.w);
  *(ushort4*)(out + (size_t)which * 1048576 + i) = o;
}

// ---------------- pack mask int32 -> bit per element ----------------
__global__ __launch_bounds__(256) void pack_mask(const int* __restrict__ mask,
                                                 u64* __restrict__ bits) {
  int wave = (blockIdx.x * 256 + threadIdx.x) >> 6;
  int lane = threadIdx.x & 63;
  const int* row = mask + (size_t)wave * NSEQ;
  u64* out = bits + (size_t)wave * 32;
  for (int c = 0; c < 32; ++c) {
    int v = row[c * 64 + lane];
    u64 bl = __ballot(v != 0);
    if (lane == 0) out[c] = bl;
  }
}

// ---------------- fused QKV GEMM: C[m,n] = sum_k A[m,k]*Wc[n,k], N=3072 ----------------
// bn 0..7 -> Q [B,H,N,64]; 8..15 -> K [B,H,N,64]; 16..23 -> V^T [B,H,64,NSEQ]
__global__ __launch_bounds__(256) void gemm_qkv(const u16* __restrict__ A,
                                                const u16* __restrict__ Wc,
                                                u16* __restrict__ qo,
                                                u16* __restrict__ ko,
                                                u16* __restrict__ vo) {
  __shared__ __align__(16) u16 Al[128 * 64];
  __shared__ __align__(16) u16 Bl[128 * 64];
  const int tid = threadIdx.x;
  const int w = tid >> 6, l = tid & 63;
  const int l15 = l & 15, l4 = l >> 4;
  const int bm = blockIdx.x, bn = blockIdx.y;
  const int wm = w >> 1, wn = w & 1;

  f32x4 acc[4][4] = {};

  for (int ks = 0; ks < 1024; ks += 64) {
    __syncthreads();
#pragma unroll
    for (int c = 0; c < 4; ++c) {
      int g = w * 256 + c * 64 + l;
      int row = g >> 3, gc = g & 7;
      int sgc = gc ^ (row & 7);
      gload_lds16(A + (size_t)(bm * 128 + row) * 1024 + ks + sgc * 8, &Al[g * 8]);
      gload_lds16(Wc + (size_t)(bn * 128 + row) * 1024 + ks + sgc * 8, &Bl[g * 8]);
    }
    __syncthreads();
#pragma unroll
    for (int kc = 0; kc < 2; ++kc) {
      bf16x8 af[4], bfr[4];
#pragma unroll
      for (int mi = 0; mi < 4; ++mi) {
        int row = wm * 64 + mi * 16 + l15;
        int gc2 = (kc * 4 + l4) ^ (row & 7);
        af[mi] = *(const bf16x8*)&Al[row * 64 + gc2 * 8];
      }
#pragma unroll
      for (int ni = 0; ni < 4; ++ni) {
        int row = wn * 64 + ni * 16 + l15;
        int gc2 = (kc * 4 + l4) ^ (row & 7);
        bfr[ni] = *(const bf16x8*)&Bl[row * 64 + gc2 * 8];
      }
#pragma unroll
      for (int mi = 0; mi < 4; ++mi)
#pragma unroll
        for (int ni = 0; ni < 4; ++ni)
          acc[mi][ni] = __builtin_amdgcn_mfma_f32_16x16x32_bf16(af[mi], bfr[ni],
                                                                acc[mi][ni], 0, 0, 0);
    }
  }

  const int which = bn >> 3;
#pragma unroll
  for (int mi = 0; mi < 4; ++mi)
#pragma unroll
    for (int ni = 0; ni < 4; ++ni)
#pragma unroll
      for (int r = 0; r < 4; ++r) {
        int m = bm * 128 + wm * 64 + mi * 16 + l4 * 4 + r;
        int n = (bn & 7) * 128 + wn * 64 + ni * 16 + l15;
        int b = m >> 11, row = m & 2047, h = n >> 6, d = n & 63;
        u16 val = f2bf(acc[mi][ni][r]);
        size_t bh = (size_t)(b * 16 + h);
        if (which == 0)      qo[(bh * NSEQ + row) * 64 + d] = val;
        else if (which == 1) ko[(bh * NSEQ + row) * 64 + d] = val;
        else                 vo[(bh * 64 + d) * NSEQ + row] = val;
      }
}

// ---------------- final GEMM: out[m,n] = sum_k A[m,k]*W[n,k], fp32 out ----------------
__global__ __launch_bounds__(256) void gemm_out(const u16* __restrict__ A,
                                                const u16* __restrict__ W,
                                                float* __restrict__ C) {
  __shared__ __align__(16) u16 Al[128 * 64];
  __shared__ __align__(16) u16 Bl[128 * 64];
  const int tid = threadIdx.x;
  const int w = tid >> 6, l = tid & 63;
  const int l15 = l & 15, l4 = l >> 4;
  const int bm = blockIdx.x, bn = blockIdx.y;
  const int wm = w >> 1, wn = w & 1;

  f32x4 acc[4][4] = {};

  for (int ks = 0; ks < 1024; ks += 64) {
    __syncthreads();
#pragma unroll
    for (int c = 0; c < 4; ++c) {
      int g = w * 256 + c * 64 + l;
      int row = g >> 3, gc = g & 7;
      int sgc = gc ^ (row & 7);
      gload_lds16(A + (size_t)(bm * 128 + row) * 1024 + ks + sgc * 8, &Al[g * 8]);
      gload_lds16(W + (size_t)(bn * 128 + row) * 1024 + ks + sgc * 8, &Bl[g * 8]);
    }
    __syncthreads();
#pragma unroll
    for (int kc = 0; kc < 2; ++kc) {
      bf16x8 af[4], bfr[4];
#pragma unroll
      for (int mi = 0; mi < 4; ++mi) {
        int row = wm * 64 + mi * 16 + l15;
        int gc2 = (kc * 4 + l4) ^ (row & 7);
        af[mi] = *(const bf16x8*)&Al[row * 64 + gc2 * 8];
      }
#pragma unroll
      for (int ni = 0; ni < 4; ++ni) {
        int row = wn * 64 + ni * 16 + l15;
        int gc2 = (kc * 4 + l4) ^ (row & 7);
        bfr[ni] = *(const bf16x8*)&Bl[row * 64 + gc2 * 8];
      }
#pragma unroll
      for (int mi = 0; mi < 4; ++mi)
#pragma unroll
        for (int ni = 0; ni < 4; ++ni)
          acc[mi][ni] = __builtin_amdgcn_mfma_f32_16x16x32_bf16(af[mi], bfr[ni],
                                                                acc[mi][ni], 0, 0, 0);
    }
  }

#pragma unroll
  for (int mi = 0; mi < 4; ++mi)
#pragma unroll
    for (int ni = 0; ni < 4; ++ni)
#pragma unroll
      for (int r = 0; r < 4; ++r) {
        int m = bm * 128 + wm * 64 + mi * 16 + l4 * 4 + r;
        int n = bn * 128 + wn * 64 + ni * 16 + l15;
        C[(size_t)m * 1024 + n] = acc[mi][ni][r];
      }
}

// ---------------- flash attention ----------------
// Swapped QK^T + register softmax + K-row permutation (PV A-slots standard,
// V as b128, P direct from cvt_pk regs). alibi/mask prefetched (t+1) into
// registers; counted-vmcnt raw barrier. Block decode: BATCH INNERMOST so the
// 4 batch-siblings sharing alibi[h] rows are dispatch-adjacent (same XCD L2).
__global__ __launch_bounds__(256, 4) void attn_kernel(
    const u16* __restrict__ q, const u16* __restrict__ k, const u16* __restrict__ vT,
    const float* __restrict__ alibi, const u64* __restrict__ mbits,
    u16* __restrict__ o) {
  __shared__ __align__(16) u16 Kl[2][64 * 64];
  __shared__ __align__(16) u16 Vl[2][64 * 64];

  const int tid = threadIdx.x, w = tid >> 6, l = tid & 63;
  const int l15 = l & 15, l4 = l >> 4;
  const int W = blockIdx.x;
  const int W2 = (W & 7) * 256 + (W >> 3);
  // batch innermost: siblings b=0..3 adjacent -> alibi L2 reuse by construction
  const int b = W2 & 3, hq = W2 >> 2;
  const int qb = hq & 31, h = hq >> 5;
  const int bh = b * 16 + h;
  const int wq0 = qb * 64 + w * 16;
  const int myq = wq0 + l15;

  // Q fragment (rows = l15)
  bf16x8 aq[2];
  {
    const u16* qrow = q + ((size_t)bh * NSEQ + myq) * 64;
    aq[0] = *(const bf16x8*)(qrow + l4 * 8);
    aq[1] = *(const bf16x8*)(qrow + 32 + l4 * 8);
  }

  // staging pointers. K rows permuted: LDS row p holds global row
  // 32*(p>>5) + 8*((p>>2)&3) + 4*((p>>4)&1) + (p&3)  -> S^T k-distribution
  // matches the standard PV A-slot order.
  const u16* kg[2]; const u16* vg[2];
#pragma unroll
  for (int c = 0; c < 2; ++c) {
    int g = w * 128 + c * 64 + l;
    int row = g >> 3, gc = g & 7, sgc = gc ^ (row & 7);
    int srow = (row & 0x23) | (((row >> 2) & 3) << 3) | (((row >> 4) & 1) << 2);
    kg[c] = k + ((size_t)bh * NSEQ + srow) * 64 + sgc * 8;
    vg[c] = vT + ((size_t)bh * 64 + row) * NSEQ + sgc * 8;
  }

  // per-lane alibi / mask pointers (permuted k: lane covers k = 8*l4 + {0..7} + 32c)
  const float* alp = alibi + (size_t)h * NSEQ * NSEQ + (size_t)myq * NSEQ + 8 * l4;
  const u64* mrp = mbits + ((size_t)b * NSEQ + myq) * 32;

  // LDS read offsets (K and V identical pattern)
  const int kfr[2] = { l15 * 128 + (((0 + l4) ^ (l15 & 7)) << 4),
                       l15 * 128 + (((4 + l4) ^ (l15 & 7)) << 4) };

  f32x4 oacc[4] = {};          // q = wq0 + l4*4 + r, d = db*16 + l15
  float m_run = -3.0e38f, l_run = 0.f;

  auto stage = [&](u16* KB, u16* VB) {
#pragma unroll
    for (int c = 0; c < 2; ++c) {
      gload_lds16(kg[c], (char*)KB + (w * 128 + c * 64 + l) * 16);
      kg[c] += 4096;
      gload_lds16(vg[c], (char*)VB + (w * 128 + c * 64 + l) * 16);
      vg[c] += 64;
    }
  };

  auto loadal = [&](float4* a, u64& m, int t) {
    a[0] = *(const float4*)(alp + t * 64);
    a[1] = *(const float4*)(alp + t * 64 + 4);
    a[2] = *(const float4*)(alp + t * 64 + 32);
    a[3] = *(const float4*)(alp + t * 64 + 36);
    m = mrp[t];
  };

  float4 alA[4], alB[4];
  u64 mbA, mbB;

  stage(Kl[0], Vl[0]);
  loadal(alA, mbA, 0);

  auto body = [&](const u16* KB, const u16* VB, u16* KN, u16* VN,
                  const float4* alc, u64 mbc, float4* aln, u64& mbn,
                  int t, bool dost) {
    if (dost) {
      loadal(aln, mbn, t + 1);
      asm volatile("s_waitcnt vmcnt(5)" ::: "memory");
    } else {
      asm volatile("s_waitcnt vmcnt(0)" ::: "memory");
    }
    __builtin_amdgcn_s_barrier();
    if (dost) stage(KN, VN);

    // S^T = K Q^T : lane q=l15; k rows permuted by staging
    __builtin_amdgcn_s_setprio(1);
    f32x4 st[4];
#pragma unroll
    for (int kb = 0; kb < 4; ++kb) {
      f32x4 z = {0.f, 0.f, 0.f, 0.f};
      st[kb] = z;
#pragma unroll
      for (int kc = 0; kc < 2; ++kc) {
        bf16x8 bk = *(const bf16x8*)((const char*)KB + kfr[kc] + kb * 2048);
        st[kb] = __builtin_amdgcn_mfma_f32_16x16x32_bf16(bk, aq[kc], st[kb], 0, 0, 0);
      }
    }
    __builtin_amdgcn_s_setprio(0);

    // scale + alibi (permuted layout: (kb,r) -> global k = 32*(kb>>1)+8*l4+4*(kb&1)+r)
#pragma unroll
    for (int kb = 0; kb < 4; ++kb)
#pragma unroll
      for (int r = 0; r < 4; ++r)
        st[kb][r] = fmaf(st[kb][r], ATT_SCALE, alc[kb][r]);
    if (!__all(mbc == ~0ull)) {
#pragma unroll
      for (int kb = 0; kb < 4; ++kb)
#pragma unroll
        for (int r = 0; r < 4; ++r) {
          int bit = 32 * (kb >> 1) + 8 * l4 + 4 * (kb & 1) + r;
          if (!((mbc >> bit) & 1)) st[kb][r] = -3.0e38f;
        }
    }

    // row max: in-lane tree + xor16 + xor32
    float m0 = fmaxf(fmaxf(st[0][0], st[0][1]), fmaxf(st[0][2], st[0][3]));
    float m1 = fmaxf(fmaxf(st[1][0], st[1][1]), fmaxf(st[1][2], st[1][3]));
    float m2 = fmaxf(fmaxf(st[2][0], st[2][1]), fmaxf(st[2][2], st[2][3]));
    float m3 = fmaxf(fmaxf(st[3][0], st[3][1]), fmaxf(st[3][2], st[3][3]));
    float tm = fmaxf(fmaxf(m0, m1), fmaxf(m2, m3));
    tm = fmaxf(tm, __shfl_xor(tm, 16));
    tm = fmaxf(tm, __shfl_xor(tm, 32));

    // defer-max rescale
    if (__any(tm > m_run + 4.0f)) {
      float mn = fmaxf(m_run, tm);
      float fac = exp2f((m_run - mn) * LOG2E);
      l_run *= fac;
      m_run = mn;
#pragma unroll
      for (int r = 0; r < 4; ++r) {
        float fr = __shfl(fac, l4 * 4 + r);
#pragma unroll
        for (int db = 0; db < 4; ++db) oacc[db][r] *= fr;
      }
    }

    // exp + sum
    float negm = -m_run * LOG2E;
    float p[16];
#pragma unroll
    for (int kb = 0; kb < 4; ++kb)
#pragma unroll
      for (int r = 0; r < 4; ++r)
        p[kb * 4 + r] = exp2f(fmaf(st[kb][r], LOG2E, negm));
    float s0 = (p[0] + p[1]) + (p[2] + p[3]);
    float s1 = (p[4] + p[5]) + (p[6] + p[7]);
    float s2 = (p[8] + p[9]) + (p[10] + p[11]);
    float s3 = (p[12] + p[13]) + (p[14] + p[15]);
    float ts = (s0 + s1) + (s2 + s3);
    ts += __shfl_xor(ts, 16);
    ts += __shfl_xor(ts, 32);
    l_run += ts;

    // pack P -> bf16 pairs; standard A-slots: pa[c] slot j <-> global k = 32c+8*l4+j
    u32 Wp[8];
#pragma unroll
    for (int i = 0; i < 8; ++i)
      asm("v_cvt_pk_bf16_f32 %0, %1, %2" : "=v"(Wp[i]) : "v"(p[2 * i]), "v"(p[2 * i + 1]));

    // O += P V  (V as contiguous b128, same swizzle pattern as K)
    __builtin_amdgcn_s_setprio(1);
#pragma unroll
    for (int c = 0; c < 2; ++c) {
      u32x4 wv = {Wp[4 * c], Wp[4 * c + 1], Wp[4 * c + 2], Wp[4 * c + 3]};
      bf16x8 pa = __builtin_bit_cast(bf16x8, wv);
#pragma unroll
      for (int db = 0; db < 4; ++db) {
        bf16x8 bv = *(const bf16x8*)((const char*)VB + kfr[c] + db * 2048);
        oacc[db] = __builtin_amdgcn_mfma_f32_16x16x32_bf16(pa, bv, oacc[db], 0, 0, 0);
      }
    }
    __builtin_amdgcn_s_setprio(0);
  };

  for (int t2 = 0; t2 < 16; ++t2) {
    body(Kl[0], Vl[0], Kl[1], Vl[1], alA, mbA, alB, mbB, t2 * 2, true);
    body(Kl[1], Vl[1], Kl[0], Vl[0], alB, mbB, alA, mbA, t2 * 2 + 1, t2 < 15);
  }

  // normalize + write O (q = wq0 + l4*4 + r, d = db*16 + l15)
#pragma unroll
  for (int r = 0; r < 4; ++r) {
    float lr = __shfl(l_run, l4 * 4 + r);
    float inv = __builtin_amdgcn_rcpf(lr);
    int qq = wq0 + l4 * 4 + r;
#pragma unroll
    for (int db = 0; db < 4; ++db) {
      int d = db * 16 + l15;
      o[((size_t)b * NSEQ + qq) * DMODEL + h * 64 + d] = f2bf(oacc[db][r] * inv);
    }
  }
}

extern "C" void kernel_launch(void* const* d_in, const int* in_sizes, int n_in,
                              void* d_out, int out_size, void* d_ws, size_t ws_size,
                              hipStream_t stream) {
  (void)in_sizes; (void)n_in; (void)out_size; (void)ws_size;
  const float* x = (const float*)d_in[0];
  const int* mask = (const int*)d_in[1];
  const float* alibi = (const float*)d_in[2];
  const float* Wq = (const float*)d_in[3];
  const float* Wk = (const float*)d_in[4];
  const float* Wv = (const float*)d_in[5];
  const float* Wo = (const float*)d_in[6];
  float* out = (float*)d_out;

  char* ws = (char*)d_ws;
  const size_t MB = 1u << 20;
  u16* xb  = (u16*)(ws + 0 * MB);    // 16 MB
  u16* wqb = (u16*)(ws + 16 * MB);   // 8 MB (wq,wk,wv,wo contiguous)
  u16* wob = (u16*)(ws + 22 * MB);
  u16* qb  = (u16*)(ws + 24 * MB);   // 16 MB  [B,H,N,64]
  u16* kb  = (u16*)(ws + 40 * MB);   // 16 MB  [B,H,N,64]
  u16* vT  = (u16*)(ws + 56 * MB);   // 16 MB  [B,H,64,N]
  u16* ob  = (u16*)(ws + 72 * MB);   // 16 MB  [B,N,1024]
  u64* mbits = (u64*)(ws + 88 * MB); // 2 MB   [B*N][32]

  cast_f32_bf16<<<8192, 256, 0, stream>>>(x, xb, MTOT * DMODEL);
  cast_w4<<<4096, 256, 0, stream>>>(Wq, Wk, Wv, Wo, wqb);
  pack_mask<<<2048, 256, 0, stream>>>(mask, mbits);

  gemm_qkv<<<dim3(64, 24), 256, 0, stream>>>(xb, wqb, qb, kb, vT);

  attn_kernel<<<2048, 256, 0, stream>>>(qb, kb, vT, alibi, mbits, ob);

  gemm_out<<<dim3(64, 8), 256, 0, stream>>>(ob, wob, out);
}